// Round 6
// baseline (590.276 us; speedup 1.0000x reference)
//
#include <hip/hip_runtime.h>
#include <hip/hip_fp16.h>

#define D 64
#define NKR 16
#define NB 1024
#define NL 8

typedef __attribute__((ext_vector_type(8))) _Float16 half8;
typedef __attribute__((ext_vector_type(16))) float f32x16;
typedef __attribute__((ext_vector_type(4))) int i32x4;

static __device__ __forceinline__ half8 neg8(half8 x) {
    i32x4 u = __builtin_bit_cast(i32x4, x);
    u = u ^ (int)0x80008000;
    return __builtin_bit_cast(half8, u);
}

union Pack4 { _Float16 h[4]; uint2 u; };
union H8U { half8 h; uint2 u2[2]; };

#define GLDS16(gp, lp) \
    __builtin_amdgcn_global_load_lds((const __attribute__((address_space(1))) void*)(gp), \
                                     (__attribute__((address_space(3))) void*)(lp), 16, 0, 0)

#define MFMA32(A, B, C) __builtin_amdgcn_mfma_f32_32x32x16_f16((A), (B), (C), 0, 0, 0)

// kraus fp32 -> fp16, layout [L][K][2][64][64] with XOR-swizzled 16B granules:
// element (plane,row,col) -> plane*4096 + row*64 + ((col>>3)^(row&7))*8 + (col&7)
__global__ void kconv_kernel(const float* __restrict__ re, const float* __restrict__ im,
                             _Float16* __restrict__ out) {
    int plane = blockIdx.y;
    int idx = blockIdx.x * blockDim.x + threadIdx.x;
    const float* src = plane ? im : re;
    float4 v = ((const float4*)src)[idx];
    int e = idx * 4;
    int lk = e >> 12;
    int rem = e & 4095;
    int row = rem >> 6, col = rem & 63;
    int grp = (col >> 3) ^ (row & 7);
    Pack4 p;
    p.h[0] = (_Float16)v.x; p.h[1] = (_Float16)v.y;
    p.h[2] = (_Float16)v.z; p.h[3] = (_Float16)v.w;
    *(uint2*)(out + ((size_t)lk * 2 + plane) * 4096 + row * 64 + grp * 8 + (col & 7)) = p.u;
}

// state fp32 -> fp16 transposed: out[b][plane][l][j] = state[b][j][l]
__global__ void sconv_kernel(const float* __restrict__ re, const float* __restrict__ im,
                             _Float16* __restrict__ out) {
    __shared__ float tile[64][65];
    int b = blockIdx.x;
    int t = threadIdx.x;
    for (int plane = 0; plane < 2; ++plane) {
        const float* src = (plane ? im : re) + (size_t)b * 4096;
        __syncthreads();
        #pragma unroll
        for (int i = 0; i < 16; ++i) {
            int e = t + 256 * i;
            tile[e >> 6][e & 63] = src[e];
        }
        __syncthreads();
        _Float16* o = out + ((size_t)b * 2 + plane) * 4096;
        #pragma unroll
        for (int i = 0; i < 16; ++i) {
            int e = t + 256 * i;            // e = l*64 + j
            o[e] = (_Float16)tile[e & 63][e >> 6];
        }
    }
}

// One block per rho; 4 waves: wr = wv>>1 (l-chunk), wc = wv&1 (i-tile).
// Per kraus k (single 16 KB Klds buffer, R4-validated barrier discipline):
//   [Klds holds K_k]  ds_read all B-frags (s1 x8, o2 x4)
//   __syncthreads()   -> every wave's reads drained (lgkmcnt0 at barrier entry)
//   prefetch K_{k+1} via global_load_lds (overwrites Klds, now safe)
//   stage1 MFMAs -> in-register shfl_xor(32) transpose -> stage2 MFMAs (no LDS!)
//   __syncthreads()   -> prefetch drained (vmcnt0 at barrier entry)
// Cross-wave l-reduction once per layer through a DEDICATED Red array.
__global__ __launch_bounds__(256, 2) void layer_kernel(
    const _Float16* __restrict__ rho_in,
    _Float16* __restrict__ rho_out,
    float* __restrict__ final_out,
    const _Float16* __restrict__ kraus,   // this layer, swizzled: [K][2][64][64]
    int last)
{
    __shared__ __align__(16) _Float16 Klds[2 * D * D];   // 16 KB
    __shared__ __align__(16) float Red[2][4096];         // 32 KB reduction scratch

    const int b    = blockIdx.x;
    const int t    = threadIdx.x;
    const int wv   = t >> 6;
    const int lane = t & 63;
    const int l31  = lane & 31;
    const int hl   = lane >> 5;
    const int wr   = wv >> 1;
    const int wc   = wv & 1;

    // ks order: entries 2,3 are ks = 2wr, 2wr+1 (their B-frags feed stage2's l-chunk)
    const int ksA = (2 * wr) ^ 2;
    const int kord[4] = { ksA, ksA + 1, 2 * wr, 2 * wr + 1 };

    // ---- A1 fragments: rho^T row l = 32wr + l31, j-chunks in kord order ----
    half8 a1re[4], a1im[4];
    {
        const _Float16* rb = rho_in + (size_t)b * 2 * D * D;
        const int row = 32 * wr + l31;
        #pragma unroll
        for (int o = 0; o < 4; ++o) {
            const int col = 16 * kord[o] + 8 * hl;
            a1re[o] = *(const half8*)(rb + row * D + col);
            a1im[o] = *(const half8*)(rb + D * D + row * D + col);
        }
    }

    // ---- preload K_0 ----
    {
        const char* kg = (const char*)kraus;
        char* lb = (char*)Klds + wv * 4096;
        #pragma unroll
        for (int rr = 0; rr < 4; ++rr)
            GLDS16(kg + wv * 4096 + rr * 1024 + lane * 16, lb + rr * 1024);
    }

    f32x16 acc[4];   // 0: Re (m-half wc)  1: Re (m-half 1-wc)  2: Im (wc)  3: Im (1-wc)
    #pragma unroll
    for (int q = 0; q < 4; ++q)
        #pragma unroll
        for (int i = 0; i < 16; ++i) acc[q][i] = 0.f;

    const int rowS = 32 * wc + l31;         // stage1 B rows (=i) & stage2 m-half wc
    const int rowO = 32 * (1 - wc) + l31;   // stage2 other m-half
    const int rxS = rowS & 7, rxO = rowO & 7;

    __syncthreads();   // K_0 staged

    #pragma unroll 1
    for (int k = 0; k < NKR; ++k) {
        // ---- all B-frags for this kraus (only LDS access in the loop) ----
        half8 s1re[4], s1im[4], o2re[2], o2im[2];
        #pragma unroll
        for (int o = 0; o < 4; ++o) {
            const int g = ((2 * kord[o] + hl) ^ rxS) * 8;
            s1re[o] = *(const half8*)(Klds + rowS * 64 + g);
            s1im[o] = *(const half8*)(Klds + 4096 + rowS * 64 + g);
        }
        #pragma unroll
        for (int c = 0; c < 2; ++c) {
            const int g = ((4 * wr + 2 * c + hl) ^ rxO) * 8;
            o2re[c] = *(const half8*)(Klds + rowO * 64 + g);
            o2im[c] = *(const half8*)(Klds + 4096 + rowO * 64 + g);
        }
        __syncthreads();   // every wave's Klds reads complete -> safe to overwrite

        // ---- prefetch K_{k+1}; flies under all 32 MFMAs below ----
        if (k + 1 < NKR) {
            const char* kg = (const char*)(kraus + (size_t)(k + 1) * 2 * D * D);
            char* lb = (char*)Klds + wv * 4096;
            #pragma unroll
            for (int rr = 0; rr < 4; ++rr)
                GLDS16(kg + wv * 4096 + rr * 1024 + lane * 16, lb + rr * 1024);
        }

        // ---- stage 1: X = rho^T K^T (rows l in 32wr, cols i in 32wc) ----
        f32x16 dre, dim_;
        #pragma unroll
        for (int i = 0; i < 16; ++i) { dre[i] = 0.f; dim_[i] = 0.f; }
        #pragma unroll
        for (int o = 0; o < 4; ++o) {
            dre  = MFMA32(a1re[o], s1re[o], dre);
            dre  = MFMA32(a1im[o], neg8(s1im[o]), dre);
            dim_ = MFMA32(a1re[o], s1im[o], dim_);
            dim_ = MFMA32(a1im[o], s1re[o], dim_);
        }

        // ---- in-register transpose: lane holds X[l_loc=8g+4hl+j][i=32wc+l31];
        //      build stage2 A-frags T[i][l-chunk c]: need l_off = 16c+8hl+j'.
        //      hl=0 keeps g=2c (j'=0..3), recv partner g=2c   (j'=4..7);
        //      hl=1 recv partner g=2c+1 (j'=0..3), keeps g=2c+1 (j'=4..7).
        half8 tre[2], tim[2];
        {
            Pack4 gr[4], gi[4];
            #pragma unroll
            for (int g = 0; g < 4; ++g)
                #pragma unroll
                for (int j = 0; j < 4; ++j) {
                    gr[g].h[j] = (_Float16)dre[4 * g + j];
                    gi[g].h[j] = (_Float16)dim_[4 * g + j];
                }
            #pragma unroll
            for (int c = 0; c < 2; ++c) {
                uint2 sr = hl ? gr[2 * c].u : gr[2 * c + 1].u;
                uint2 si = hl ? gi[2 * c].u : gi[2 * c + 1].u;
                uint2 rr, ri;
                rr.x = __shfl_xor((int)sr.x, 32, 64);
                rr.y = __shfl_xor((int)sr.y, 32, 64);
                ri.x = __shfl_xor((int)si.x, 32, 64);
                ri.y = __shfl_xor((int)si.y, 32, 64);
                H8U ur, ui;
                ur.u2[0] = hl ? rr : gr[2 * c].u;
                ur.u2[1] = hl ? gr[2 * c + 1].u : rr;
                ui.u2[0] = hl ? ri : gi[2 * c].u;
                ui.u2[1] = hl ? gi[2 * c + 1].u : ri;
                tre[c] = ur.h;
                tim[c] = ui.h;
            }
        }

        // ---- stage 2: S[i in 32wc][m] += T * conj(K), l-chunk 32wr, both m-halves ----
        #pragma unroll
        for (int c = 0; c < 2; ++c) {
            half8 tren = neg8(tre[c]);
            acc[0] = MFMA32(tre[c], s1re[2 + c], acc[0]);
            acc[0] = MFMA32(tim[c], s1im[2 + c], acc[0]);
            acc[2] = MFMA32(tim[c], s1re[2 + c], acc[2]);
            acc[2] = MFMA32(tren,   s1im[2 + c], acc[2]);
            acc[1] = MFMA32(tre[c], o2re[c], acc[1]);
            acc[1] = MFMA32(tim[c], o2im[c], acc[1]);
            acc[3] = MFMA32(tim[c], o2re[c], acc[3]);
            acc[3] = MFMA32(tren,   o2im[c], acc[3]);
        }
        __syncthreads();   // prefetch drained (vmcnt0) before next iter's reads
    }

    // ---- cross-wave l-reduction: wr==1 dumps, wr==0 adds (dedicated Red array) ----
    float* red = &Red[wc][0];
    if (wr == 1) {
        #pragma unroll
        for (int q = 0; q < 4; ++q)
            #pragma unroll
            for (int g = 0; g < 4; ++g) {
                float4 v = make_float4(acc[q][4 * g], acc[q][4 * g + 1],
                                       acc[q][4 * g + 2], acc[q][4 * g + 3]);
                *(float4*)(red + ((q * 4 + g) * 64 + lane) * 4) = v;
            }
    }
    __syncthreads();
    if (wr == 0) {
        #pragma unroll
        for (int q = 0; q < 4; ++q)
            #pragma unroll
            for (int g = 0; g < 4; ++g) {
                float4 v = *(const float4*)(red + ((q * 4 + g) * 64 + lane) * 4);
                acc[q][4 * g] += v.x; acc[q][4 * g + 1] += v.y;
                acc[q][4 * g + 2] += v.z; acc[q][4 * g + 3] += v.w;
            }

        // ---- epilogue: acc cols m = m_base + l31; reg 4g+j -> row i = 32wc+8g+4hl+j ----
        const int ibase = 32 * wc;
        if (!last) {
            _Float16* ob = rho_out + (size_t)b * 2 * D * D;
            #pragma unroll
            for (int tt = 0; tt < 2; ++tt) {
                const int m = (tt ? 32 * (1 - wc) : 32 * wc) + l31;
                #pragma unroll
                for (int g = 0; g < 4; ++g) {
                    Pack4 pr, pi;
                    #pragma unroll
                    for (int j = 0; j < 4; ++j) {
                        pr.h[j] = (_Float16)acc[tt][4 * g + j];          // Re: q=0/1
                        pi.h[j] = (_Float16)acc[2 + tt][4 * g + j];      // Im: q=2/3
                    }
                    const int i0 = ibase + 8 * g + 4 * hl;
                    *(uint2*)(ob + m * D + i0)         = pr.u;   // rho_new^T[m][i]
                    *(uint2*)(ob + D * D + m * D + i0) = pi.u;
                }
            }
        } else {
            float* o0 = final_out + (size_t)b * 4096;            // [0][b][i][m]
            float* o1 = final_out + (size_t)(NB + b) * 4096;     // [1][b][i][m]
            #pragma unroll
            for (int tt = 0; tt < 2; ++tt) {
                const int m = (tt ? 32 * (1 - wc) : 32 * wc) + l31;
                #pragma unroll
                for (int g = 0; g < 4; ++g)
                    #pragma unroll
                    for (int j = 0; j < 4; ++j) {
                        const int i = ibase + 8 * g + 4 * hl + j;
                        o0[i * D + m] = acc[tt][4 * g + j];
                        o1[i * D + m] = acc[2 + tt][4 * g + j];
                    }
            }
        }
    }
}

extern "C" void kernel_launch(void* const* d_in, const int* in_sizes, int n_in,
                              void* d_out, int out_size, void* d_ws, size_t ws_size,
                              hipStream_t stream) {
    const float* state_re = (const float*)d_in[0];
    const float* state_im = (const float*)d_in[1];
    const float* kraus_re = (const float*)d_in[2];
    const float* kraus_im = (const float*)d_in[3];

    _Float16* kraus_h = (_Float16*)d_ws;                         // 2 MB in ws (swizzled)
    // ping-pong rho buffers live inside d_out (2 x 16 MB = out_size exactly).
    // Safe: each block reads its rho only in the hoisted prologue, writes only in
    // the epilogue (block-local read-before-write on the final layer).
    _Float16* bufA = (_Float16*)d_out;
    _Float16* bufB = (_Float16*)((char*)d_out + (size_t)NB * 2 * D * D * sizeof(_Float16));
    float* fout = (float*)d_out;

    kconv_kernel<<<dim3(512, 2), 256, 0, stream>>>(kraus_re, kraus_im, kraus_h);
    sconv_kernel<<<NB, 256, 0, stream>>>(state_re, state_im, bufA);

    for (int l = 0; l < NL; ++l) {
        const _Float16* in = (l & 1) ? bufB : bufA;
        _Float16* out      = (l & 1) ? bufA : bufB;
        layer_kernel<<<NB, 256, 0, stream>>>(in, out, fout,
                                             kraus_h + (size_t)l * NKR * 2 * D * D,
                                             (l == NL - 1) ? 1 : 0);
    }
}